// Round 6
// baseline (939.428 us; speedup 1.0000x reference)
//
#include <hip/hip_runtime.h>
#include <hip/hip_bf16.h>
#include <math.h>

// Problem constants
#define BB   64
#define TT   2048
#define DD   8        // LATENT
#define HH   64       // HID
#define LLEN 2046     // length = TT - LAGS
#define NN   (BB*LLEN) // 130944
#define GIN  81       // HID + LAGS*LATENT + 1
#define NG64 (NN/64)  // 2046 sample-groups of 64
#define SW   66       // Z row stride in dwords (64 + 2 pad)

// ---------------------------------------------------------------------------
// Embedding MLP (as round 1; output layout now 64-sample k-major groups)
// ---------------------------------------------------------------------------
template<int K, bool ACT>
__device__ __forceinline__ void fwd_layer(float* zr,
                                          const float* __restrict__ W,
                                          const float* __restrict__ bias)
{
    float acc[HH];
#pragma unroll
    for (int j = 0; j < HH; ++j) acc[j] = bias[j];
    for (int k = 0; k < K; ++k) {
        const float zk = zr[k];
        const float* wr = W + k * HH;
#pragma unroll
        for (int j = 0; j < HH; ++j) acc[j] = fmaf(zk, wr[j], acc[j]);
    }
#pragma unroll
    for (int j = 0; j < HH; ++j) {
        float v = acc[j];
        if (ACT) v = (v >= 0.f) ? v : 0.1f * v;
        zr[j] = v;
    }
}

__global__ __launch_bounds__(192) void emb_mlp_kernel(
    const float* __restrict__ emb_in,
    const float* __restrict__ W1, const float* __restrict__ b1,
    const float* __restrict__ Wh, const float* __restrict__ bh,
    const float* __restrict__ W2, const float* __restrict__ b2,
    float* __restrict__ embT)
{
    __shared__ float zrow[192][65];
    const int tid = threadIdx.x;
    const int n = blockIdx.x * 192 + tid;          // 682*192 == NN exact
    const int b = n / LLEN;
    const int l = n - b * LLEN;
    float* zr = zrow[tid];

    const float* ep = emb_in + ((size_t)(b * TT + (l + 2))) * 8;
    {
        float4 e0 = *(const float4*)ep;
        float4 e1 = *(const float4*)(ep + 4);
        zr[0] = e0.x; zr[1] = e0.y; zr[2] = e0.z; zr[3] = e0.w;
        zr[4] = e1.x; zr[5] = e1.y; zr[6] = e1.z; zr[7] = e1.w;
    }

    fwd_layer<8,  true >(zr, W1, b1);
    fwd_layer<HH, true >(zr, Wh,            bh);
    fwd_layer<HH, true >(zr, Wh + HH * HH,  bh + HH);
    fwd_layer<HH, false>(zr, W2, b2);

    // embT[n>>6][k][n&63] — per k, consecutive threads write consecutive addrs
    float* op = embT + ((size_t)(n >> 6)) * (HH * 64) + (n & 63);
#pragma unroll
    for (int j = 0; j < HH; ++j) op[j * 64] = zr[j];
}

// ---------------------------------------------------------------------------
// gmlp: wave = 64 samples; lane (jg,sg) owns an 8-neuron x 8-sample tile.
// Per hidden k-step: 6 imm-offset ds_read_b128 + 128 FMA (0.75 B/MAC).
// Weights phase-staged in one LDS buffer: W1 -> Wh0 -> Wh1 (barriers between).
// z/dz state round-trips through per-wave LDS rows (stride 66, linear addrs).
// ---------------------------------------------------------------------------
__global__ __launch_bounds__(256, 1) void gmlp_kernel(
    const float* __restrict__ x,
    const float* __restrict__ embT,
    const float* __restrict__ gW1, const float* __restrict__ gb1,
    const float* __restrict__ gWh, const float* __restrict__ gbh,
    const float* __restrict__ gW2, const float* __restrict__ gb2,
    float* __restrict__ resid, float* __restrict__ logd)
{
    __shared__ __align__(16) float wreg[GIN * HH];     // 20736 B (W1 / Wh0 / Wh1)
    __shared__ __align__(16) float Zb[4][128 * SW];    // 135168 B
    // total 155904 B -> 1 block/CU, 4 waves

    const int tid  = threadIdx.x;
    const int lane = tid & 63;
    const int w    = tid >> 6;
    const int d    = blockIdx.y;
    const int gid  = blockIdx.x * 4 + w;
    const bool act_w = (gid < NG64);   // 512*4 = 2048 waves vs 2046 groups

    // ---- stage W1 into LDS (all 256 threads) ----
    const float* W1g = gW1 + (size_t)d * (GIN * HH);
    for (int i = tid * 4; i < GIN * HH; i += 1024)
        *(float4*)&wreg[i] = *(const float4*)&W1g[i];

    float* Z = Zb[w];
    const int jg = lane & 7;    // j-block (8 neurons)
    const int sg = lane >> 3;   // s-block (8 samples)
    const int n0 = gid * 64;

    // ---- per-wave input staging: rows 0..63 emb, 64..79 lags, 80 x_t ----
    if (act_w) {
        const float* eb = embT + (size_t)gid * (HH * 64);
        const int kr = lane >> 4;          // 0..3
        const int sq = (lane & 15) * 4;    // sample quad
#pragma unroll
        for (int i = 0; i < 16; ++i) {
            const int k = i * 4 + kr;
            float4 v = *(const float4*)&eb[k * 64 + sq];
            *(float4*)&Z[k * SW + sq] = v;
        }
        const int n = n0 + lane;
        const int b = n / LLEN, l = n - b * LLEN;
        const float* xp = x + ((size_t)(b * TT + l)) * DD;
#pragma unroll
        for (int i = 0; i < 4; ++i) {
            float4 v = *(const float4*)(xp + i * 4);
            Z[(64 + i * 4 + 0) * SW + lane] = v.x;
            Z[(64 + i * 4 + 1) * SW + lane] = v.y;
            Z[(64 + i * 4 + 2) * SW + lane] = v.z;
            Z[(64 + i * 4 + 3) * SW + lane] = v.w;
        }
        Z[80 * SW + lane] = xp[16 + d];
    }
    __syncthreads();   // W1 staged

    // ================= phase 1: L1 (81->64, fwd) + JVP seed + publish =======
    if (act_w) {
        const float4 ba = *(const float4*)&gb1[d * HH + jg * 8];
        const float4 bb = *(const float4*)&gb1[d * HH + jg * 8 + 4];
        const float bj[8] = { ba.x, ba.y, ba.z, ba.w, bb.x, bb.y, bb.z, bb.w };
        float f[8][8];
#pragma unroll
        for (int jj = 0; jj < 8; ++jj)
#pragma unroll
            for (int ss = 0; ss < 8; ++ss) f[jj][ss] = bj[jj];

#pragma unroll 3
        for (int k = 0; k < GIN; ++k) {
            const float4 wa = *(const float4*)&wreg[k * HH + jg * 8];
            const float4 wb = *(const float4*)&wreg[k * HH + jg * 8 + 4];
            const float4 za = *(const float4*)&Z[k * SW + sg * 8];
            const float4 zc = *(const float4*)&Z[k * SW + sg * 8 + 4];
            const float wv[8] = { wa.x, wa.y, wa.z, wa.w, wb.x, wb.y, wb.z, wb.w };
            const float zv[8] = { za.x, za.y, za.z, za.w, zc.x, zc.y, zc.z, zc.w };
#pragma unroll
            for (int jj = 0; jj < 8; ++jj)
#pragma unroll
                for (int ss = 0; ss < 8; ++ss)
                    f[jj][ss] = fmaf(zv[ss], wv[jj], f[jj][ss]);
        }

        // JVP seed from W1 row 80; publish z -> rows j, dz -> rows 64+j
        const float4 wca = *(const float4*)&wreg[80 * HH + jg * 8];
        const float4 wcb = *(const float4*)&wreg[80 * HH + jg * 8 + 4];
        const float w80[8] = { wca.x, wca.y, wca.z, wca.w,
                               wcb.x, wcb.y, wcb.z, wcb.w };
#pragma unroll
        for (int jj = 0; jj < 8; ++jj) {
            float zr8[8], dr8[8];
#pragma unroll
            for (int ss = 0; ss < 8; ++ss) {
                const float m = (f[jj][ss] >= 0.f) ? 1.f : 0.1f;
                zr8[ss] = f[jj][ss] * m;
                dr8[ss] = w80[jj] * m;
            }
            const int row = jg * 8 + jj;
            float4 q;
            q = { zr8[0], zr8[1], zr8[2], zr8[3] };  *(float4*)&Z[row * SW + sg * 8]            = q;
            q = { zr8[4], zr8[5], zr8[6], zr8[7] };  *(float4*)&Z[row * SW + sg * 8 + 4]        = q;
            q = { dr8[0], dr8[1], dr8[2], dr8[3] };  *(float4*)&Z[(64 + row) * SW + sg * 8]     = q;
            q = { dr8[4], dr8[5], dr8[6], dr8[7] };  *(float4*)&Z[(64 + row) * SW + sg * 8 + 4] = q;
        }
    }
    __syncthreads();

    // fused hidden layer: reads weights from wreg, z rows 0..63, dz rows 64..127
    const float* Whg = gWh + (size_t)d * 2 * HH * HH;
    auto hidden = [&](int hl, float zo[8][8], float dzo[8][8]) {
        const float4 ba = *(const float4*)&gbh[(d * 2 + hl) * HH + jg * 8];
        const float4 bb = *(const float4*)&gbh[(d * 2 + hl) * HH + jg * 8 + 4];
        const float bj[8] = { ba.x, ba.y, ba.z, ba.w, bb.x, bb.y, bb.z, bb.w };
        float ff[8][8], dd2[8][8];
#pragma unroll
        for (int jj = 0; jj < 8; ++jj)
#pragma unroll
            for (int ss = 0; ss < 8; ++ss) { ff[jj][ss] = bj[jj]; dd2[jj][ss] = 0.f; }

#pragma unroll 2
        for (int k = 0; k < HH; ++k) {
            const float4 wa = *(const float4*)&wreg[k * HH + jg * 8];
            const float4 wb = *(const float4*)&wreg[k * HH + jg * 8 + 4];
            const float4 za = *(const float4*)&Z[k * SW + sg * 8];
            const float4 zc = *(const float4*)&Z[k * SW + sg * 8 + 4];
            const float4 da = *(const float4*)&Z[(64 + k) * SW + sg * 8];
            const float4 dc = *(const float4*)&Z[(64 + k) * SW + sg * 8 + 4];
            const float wv[8] = { wa.x, wa.y, wa.z, wa.w, wb.x, wb.y, wb.z, wb.w };
            const float zv[8] = { za.x, za.y, za.z, za.w, zc.x, zc.y, zc.z, zc.w };
            const float dv[8] = { da.x, da.y, da.z, da.w, dc.x, dc.y, dc.z, dc.w };
#pragma unroll
            for (int jj = 0; jj < 8; ++jj)
#pragma unroll
                for (int ss = 0; ss < 8; ++ss) {
                    ff[jj][ss]  = fmaf(zv[ss], wv[jj], ff[jj][ss]);
                    dd2[jj][ss] = fmaf(dv[ss], wv[jj], dd2[jj][ss]);
                }
        }
#pragma unroll
        for (int jj = 0; jj < 8; ++jj)
#pragma unroll
            for (int ss = 0; ss < 8; ++ss) {
                const float m = (ff[jj][ss] >= 0.f) ? 1.f : 0.1f;
                zo[jj][ss]  = ff[jj][ss] * m;
                dzo[jj][ss] = dd2[jj][ss] * m;
            }
    };

    // ---- stage Wh0; H1; publish ----
    for (int i = tid * 4; i < HH * HH; i += 1024)
        *(float4*)&wreg[i] = *(const float4*)&Whg[i];
    __syncthreads();

    if (act_w) {
        float z1[8][8], d1[8][8];
        hidden(0, z1, d1);
#pragma unroll
        for (int jj = 0; jj < 8; ++jj) {
            const int row = jg * 8 + jj;
            float4 q;
            q = { z1[jj][0], z1[jj][1], z1[jj][2], z1[jj][3] };  *(float4*)&Z[row * SW + sg * 8]            = q;
            q = { z1[jj][4], z1[jj][5], z1[jj][6], z1[jj][7] };  *(float4*)&Z[row * SW + sg * 8 + 4]        = q;
            q = { d1[jj][0], d1[jj][1], d1[jj][2], d1[jj][3] };  *(float4*)&Z[(64 + row) * SW + sg * 8]     = q;
            q = { d1[jj][4], d1[jj][5], d1[jj][6], d1[jj][7] };  *(float4*)&Z[(64 + row) * SW + sg * 8 + 4] = q;
        }
    }
    __syncthreads();

    // ---- stage Wh1; H2; final layer ----
    for (int i = tid * 4; i < HH * HH; i += 1024)
        *(float4*)&wreg[i] = *(const float4*)&Whg[HH * HH + i];
    __syncthreads();

    if (act_w) {
        float z2[8][8], d2[8][8];
        hidden(1, z2, d2);

        const float4 w2a = *(const float4*)&gW2[d * HH + jg * 8];
        const float4 w2b = *(const float4*)&gW2[d * HH + jg * 8 + 4];
        const float w2v[8] = { w2a.x, w2a.y, w2a.z, w2a.w,
                               w2b.x, w2b.y, w2b.z, w2b.w };
        const float b2 = gb2[d];
        float o[8], q[8];
#pragma unroll
        for (int ss = 0; ss < 8; ++ss) {
            float oo = 0.f, qq = 0.f;
#pragma unroll
            for (int jj = 0; jj < 8; ++jj) {
                oo = fmaf(z2[jj][ss], w2v[jj], oo);
                qq = fmaf(d2[jj][ss], w2v[jj], qq);
            }
            o[ss] = oo; q[ss] = qq;
        }
#pragma unroll
        for (int m = 1; m <= 4; m <<= 1)
#pragma unroll
            for (int ss = 0; ss < 8; ++ss) {
                o[ss] += __shfl_xor(o[ss], m);
                q[ss] += __shfl_xor(q[ss], m);
            }
        if (jg == 0) {
            const int nb = n0 + sg * 8;
#pragma unroll
            for (int ss = 0; ss < 8; ++ss)
                resid[(size_t)(nb + ss) * DD + d] = o[ss] + b2;
            float4 q0 = { __logf(fabsf(q[0])), __logf(fabsf(q[1])),
                          __logf(fabsf(q[2])), __logf(fabsf(q[3])) };
            float4 q1 = { __logf(fabsf(q[4])), __logf(fabsf(q[5])),
                          __logf(fabsf(q[6])), __logf(fabsf(q[7])) };
            *(float4*)&logd[(size_t)d * NN + nb]     = q0;
            *(float4*)&logd[(size_t)d * NN + nb + 4] = q1;
        }
    }
}

// ---------------------------------------------------------------------------
// log-det reduction over d
// ---------------------------------------------------------------------------
__global__ __launch_bounds__(256) void reduce_kernel(
    const float* __restrict__ logd, float* __restrict__ out)
{
    const int n = blockIdx.x * 256 + threadIdx.x;
    if (n >= NN) return;
    float s = 0.f;
#pragma unroll
    for (int d = 0; d < DD; ++d) s += logd[(size_t)d * NN + n];
    out[n] = s;
}

extern "C" void kernel_launch(void* const* d_in, const int* in_sizes, int n_in,
                              void* d_out, int out_size, void* d_ws, size_t ws_size,
                              hipStream_t stream)
{
    const float* x          = (const float*)d_in[0];
    const float* embeddings = (const float*)d_in[1];
    const float* fcW1 = (const float*)d_in[2];
    const float* fcb1 = (const float*)d_in[3];
    const float* fcWh = (const float*)d_in[4];
    const float* fcbh = (const float*)d_in[5];
    const float* fcW2 = (const float*)d_in[6];
    const float* fcb2 = (const float*)d_in[7];
    const float* gW1  = (const float*)d_in[8];
    const float* gb1  = (const float*)d_in[9];
    const float* gWh  = (const float*)d_in[10];
    const float* gbh  = (const float*)d_in[11];
    const float* gW2  = (const float*)d_in[12];
    const float* gb2  = (const float*)d_in[13];

    float* out  = (float*)d_out;
    float* embT = (float*)d_ws;                         // NN*64 floats (k-major 64-groups)
    float* logd = embT + (size_t)NN * HH;               // NN*8 floats

    emb_mlp_kernel<<<dim3(NN / 192), 192, 0, stream>>>(
        embeddings, fcW1, fcb1, fcWh, fcbh, fcW2, fcb2, embT);

    // 512 blocks/d x 4 waves = 2048 wave-groups >= 2046
    gmlp_kernel<<<dim3(512, DD), 256, 0, stream>>>(
        x, embT, gW1, gb1, gWh, gbh, gW2, gb2, out, logd);

    reduce_kernel<<<dim3((NN + 255) / 256), 256, 0, stream>>>(
        logd, out + (size_t)NN * DD);
}